// Round 3
// baseline (49.553 us; speedup 1.0000x reference)
//
#include <hip/hip_runtime.h>
#include <math.h>

#define NQ 4
#define NL 6
#define BATCH 524288
#define EPT 4  // elements per thread

struct C2 { float re, im; };

__device__ __forceinline__ C2 cmul(C2 a, C2 b) {
    return C2{ __builtin_fmaf(a.re, b.re, -a.im * b.im),
               __builtin_fmaf(a.re, b.im,  a.im * b.re) };
}

// ---------------------------------------------------------------------------
// Single fused kernel. Each block:
//   0) all threads: load x, build real Kronecker vector m[EPT][16]
//   1) lanes 0..23: build fused U = RZ*RY*RX 2x2 gates -> sU (LDS)
//   2) lanes 0..31: evolve the 16 basis columns through all 6 layers
//      (lane = 2*j + h: column j, row-half h; 8 complex amps in registers;
//      cross-half ops via __shfl_xor), fold (-i)^popcount(j) phases,
//      write V -> sV (LDS, float4 = 2 columns' (re,im))
//   3) all threads: psi = V*m, ev_q = sum_r z_q(r)|psi_r|^2, coalesced store
// ---------------------------------------------------------------------------
__global__ __launch_bounds__(256, 2) void qfused_kernel(const float4* __restrict__ x,
                                                        const float* __restrict__ w,
                                                        float4* __restrict__ out) {
    __shared__ float sU[NL * NQ * 8];
    __shared__ float4 sV4[128];  // 16 rows x 8 float4

    const int tid = threadIdx.x;
    const int base = blockIdx.x * (256 * EPT) + tid;

    // ---- 0) per-element Kronecker vector m ----
    float m[EPT][16];
#pragma unroll
    for (int e = 0; e < EPT; ++e) {
        float4 xv = x[base + e * 256];
        float c0, s0, c1, s1, c2, s2, c3, s3;
        __sincosf(0.5f * xv.x, &s0, &c0);
        __sincosf(0.5f * xv.y, &s1, &c1);
        __sincosf(0.5f * xv.z, &s2, &c2);
        __sincosf(0.5f * xv.w, &s3, &c3);
        float ab[4];
        ab[0] = c0 * c1; ab[1] = c0 * s1; ab[2] = s0 * c1; ab[3] = s0 * s1;
        float abc[8];
#pragma unroll
        for (int k = 0; k < 4; ++k) { abc[2 * k] = ab[k] * c2; abc[2 * k + 1] = ab[k] * s2; }
#pragma unroll
        for (int k = 0; k < 8; ++k) { m[e][2 * k] = abc[k] * c3; m[e][2 * k + 1] = abc[k] * s3; }
    }

    // ---- 1) fused gate matrices ----
    if (tid < NL * NQ) {
        const float a = w[tid * 3 + 0];
        const float b = w[tid * 3 + 1];
        const float g = w[tid * 3 + 2];
        float ca, sa, cb, sb, cg, sg;
        sincosf(0.5f * a, &sa, &ca);
        sincosf(0.5f * b, &sb, &cb);
        sincosf(0.5f * g, &sg, &cg);
        C2 M00{cb * ca,  sb * sa};
        C2 M01{-sb * ca, -cb * sa};
        C2 M10{sb * ca,  -cb * sa};
        C2 M11{cb * ca,  -sb * sa};
        C2 em{cg, -sg}, ep{cg, sg};
        C2 U00 = cmul(em, M00), U01 = cmul(em, M01);
        C2 U10 = cmul(ep, M10), U11 = cmul(ep, M11);
        float* o = &sU[tid * 8];
        o[0] = U00.re; o[1] = U00.im; o[2] = U01.re; o[3] = U01.im;
        o[4] = U10.re; o[5] = U10.im; o[6] = U11.re; o[7] = U11.im;
    }
    __syncthreads();

    // ---- 2) evolve basis columns (lanes 0..31 of wave 0) ----
    if (tid < 32) {
        const int j = tid >> 1;   // column
        const int h = tid & 1;    // bit3 of rows owned

        C2 st[8];
#pragma unroll
        for (int i = 0; i < 8; ++i) st[i] = C2{0.f, 0.f};
        if ((j >> 3) == h) st[j & 7].re = 1.f;

#define APPLY_PAIR(i0, i1)                                                     \
    {                                                                          \
        C2 a0 = st[i0], a1 = st[i1];                                           \
        st[i0].re = U00.re*a0.re - U00.im*a0.im + U01.re*a1.re - U01.im*a1.im; \
        st[i0].im = U00.re*a0.im + U00.im*a0.re + U01.re*a1.im + U01.im*a1.re; \
        st[i1].re = U10.re*a0.re - U10.im*a0.im + U11.re*a1.re - U11.im*a1.im; \
        st[i1].im = U10.re*a0.im + U10.im*a0.re + U11.re*a1.im + U11.im*a1.re; \
    }
#define SWAPST(a, b) { C2 t_ = st[a]; st[a] = st[b]; st[b] = t_; }

#pragma unroll
        for (int l = 0; l < NL; ++l) {
            // CNOT(q0 mask8, q1 mask4): if h==1, permute i <-> i^4
            {
                C2 ns[8];
#pragma unroll
                for (int i = 0; i < 8; ++i) {
                    ns[i].re = h ? st[i ^ 4].re : st[i].re;
                    ns[i].im = h ? st[i ^ 4].im : st[i].im;
                }
#pragma unroll
                for (int i = 0; i < 8; ++i) st[i] = ns[i];
            }
            // CNOT(q1 mask4, q2 mask2)
            SWAPST(4, 6) SWAPST(5, 7)
            // CNOT(q2 mask2, q3 mask1)
            SWAPST(2, 3) SWAPST(6, 7)
            // CNOT(q3 mask1, q0 mask8): odd rows exchange across halves
#pragma unroll
            for (int i = 1; i < 8; i += 2) {
                st[i].re = __shfl_xor(st[i].re, 1);
                st[i].im = __shfl_xor(st[i].im, 1);
            }
            // qubit 0 gate (mask 8): cross-lane
            {
                const float* u = &sU[(l * NQ + 0) * 8];
                C2 U00{u[0], u[1]}, U01{u[2], u[3]}, U10{u[4], u[5]}, U11{u[6], u[7]};
                C2 Ud = h ? U11 : U00;
                C2 Uo = h ? U10 : U01;
#pragma unroll
                for (int i = 0; i < 8; ++i) {
                    C2 p{__shfl_xor(st[i].re, 1), __shfl_xor(st[i].im, 1)};
                    C2 a = st[i];
                    st[i].re = Ud.re*a.re - Ud.im*a.im + Uo.re*p.re - Uo.im*p.im;
                    st[i].im = Ud.re*a.im + Ud.im*a.re + Uo.re*p.im + Uo.im*p.re;
                }
            }
            // qubit 1 gate (mask 4)
            {
                const float* u = &sU[(l * NQ + 1) * 8];
                C2 U00{u[0], u[1]}, U01{u[2], u[3]}, U10{u[4], u[5]}, U11{u[6], u[7]};
                APPLY_PAIR(0, 4) APPLY_PAIR(1, 5) APPLY_PAIR(2, 6) APPLY_PAIR(3, 7)
            }
            // qubit 2 gate (mask 2)
            {
                const float* u = &sU[(l * NQ + 2) * 8];
                C2 U00{u[0], u[1]}, U01{u[2], u[3]}, U10{u[4], u[5]}, U11{u[6], u[7]};
                APPLY_PAIR(0, 2) APPLY_PAIR(1, 3) APPLY_PAIR(4, 6) APPLY_PAIR(5, 7)
            }
            // qubit 3 gate (mask 1)
            {
                const float* u = &sU[(l * NQ + 3) * 8];
                C2 U00{u[0], u[1]}, U01{u[2], u[3]}, U10{u[4], u[5]}, U11{u[6], u[7]};
                APPLY_PAIR(0, 1) APPLY_PAIR(2, 3) APPLY_PAIR(4, 5) APPLY_PAIR(6, 7)
            }
        }

        // fold (-i)^popcount(j); write V to LDS: float at [r*32 + 2*j]
        const int p4 = __popc(j) & 3;
        const float fr = (p4 == 0) ? 1.f : (p4 == 2) ? -1.f : 0.f;
        const float fi = (p4 == 1) ? -1.f : (p4 == 3) ? 1.f : 0.f;
        float* sVf = reinterpret_cast<float*>(sV4);
#pragma unroll
        for (int i = 0; i < 8; ++i) {
            const int r = h * 8 + i;
            float re = st[i].re * fr - st[i].im * fi;
            float im = st[i].re * fi + st[i].im * fr;
            reinterpret_cast<float2*>(&sVf[r * 32 + 2 * j])[0] = make_float2(re, im);
        }
#undef APPLY_PAIR
#undef SWAPST
    }
    __syncthreads();

    // ---- 3) batched matvec + expectation values ----
    float ev[EPT][4];
#pragma unroll
    for (int e = 0; e < EPT; ++e)
#pragma unroll
        for (int q = 0; q < 4; ++q) ev[e][q] = 0.f;

#pragma unroll
    for (int r = 0; r < 16; ++r) {
        float4 row[8];
#pragma unroll
        for (int k = 0; k < 8; ++k) row[k] = sV4[r * 8 + k];
#pragma unroll
        for (int e = 0; e < EPT; ++e) {
            float re = 0.f, im = 0.f;
#pragma unroll
            for (int k = 0; k < 8; ++k) {
                re = __builtin_fmaf(m[e][2 * k],     row[k].x, re);
                im = __builtin_fmaf(m[e][2 * k],     row[k].y, im);
                re = __builtin_fmaf(m[e][2 * k + 1], row[k].z, re);
                im = __builtin_fmaf(m[e][2 * k + 1], row[k].w, im);
            }
            float p = __builtin_fmaf(re, re, im * im);
            if (r & 8) ev[e][0] -= p; else ev[e][0] += p;
            if (r & 4) ev[e][1] -= p; else ev[e][1] += p;
            if (r & 2) ev[e][2] -= p; else ev[e][2] += p;
            if (r & 1) ev[e][3] -= p; else ev[e][3] += p;
        }
    }

#pragma unroll
    for (int e = 0; e < EPT; ++e) {
        out[base + e * 256] = make_float4(ev[e][0], ev[e][1], ev[e][2], ev[e][3]);
    }
}

extern "C" void kernel_launch(void* const* d_in, const int* in_sizes, int n_in,
                              void* d_out, int out_size, void* d_ws, size_t ws_size,
                              hipStream_t stream) {
    const float4* x = (const float4*)d_in[0];   // [B,4] f32
    const float*  w = (const float*)d_in[1];    // [6,4,3] f32
    float4* out = (float4*)d_out;               // [B,4] f32

    const int blocks = BATCH / (256 * EPT);     // 512
    qfused_kernel<<<blocks, 256, 0, stream>>>(x, w, out);
}

// Round 4
// 38.035 us; speedup vs baseline: 1.3028x; 1.3028x over previous
//
#include <hip/hip_runtime.h>
#include <math.h>

#define NQ 4
#define NL 6
#define BATCH 524288
#define EPT 4  // elements per thread in main kernel

struct C2 { float re, im; };
typedef float f32x16 __attribute__((ext_vector_type(16)));

__device__ __forceinline__ C2 cmul(C2 a, C2 b) {
    return C2{ __builtin_fmaf(a.re, b.re, -a.im * b.im),
               __builtin_fmaf(a.re, b.im,  a.im * b.re) };
}

// ---------------------------------------------------------------------------
// Prep kernel (parallel, 1 block x 64 threads) — unchanged from R2 (verified).
// Phase 1: lanes 0..23 build fused U = RZ*RY*RX gates -> LDS.
// Phase 2: lanes 0..31 (lane = 2*j + h) evolve basis column j; 8 complex
// amps in registers; cross-half ops via __shfl_xor. Folds (-i)^popcount(j)
// and stores V[r][j] interleaved (re,im) at V[(r*16+j)*2 + {0,1}].
// ---------------------------------------------------------------------------
__global__ __launch_bounds__(64) void prep_kernel(const float* __restrict__ w,
                                                  float* __restrict__ V) {
    __shared__ float sU[NL * NQ * 8];
    const int lane = threadIdx.x;

    if (lane < NL * NQ) {
        const float a = w[lane * 3 + 0];
        const float b = w[lane * 3 + 1];
        const float g = w[lane * 3 + 2];
        float ca, sa, cb, sb, cg, sg;
        sincosf(0.5f * a, &sa, &ca);
        sincosf(0.5f * b, &sb, &cb);
        sincosf(0.5f * g, &sg, &cg);
        C2 M00{cb * ca,  sb * sa};
        C2 M01{-sb * ca, -cb * sa};
        C2 M10{sb * ca,  -cb * sa};
        C2 M11{cb * ca,  -sb * sa};
        C2 em{cg, -sg}, ep{cg, sg};
        C2 U00 = cmul(em, M00), U01 = cmul(em, M01);
        C2 U10 = cmul(ep, M10), U11 = cmul(ep, M11);
        float* o = &sU[lane * 8];
        o[0] = U00.re; o[1] = U00.im; o[2] = U01.re; o[3] = U01.im;
        o[4] = U10.re; o[5] = U10.im; o[6] = U11.re; o[7] = U11.im;
    }
    __syncthreads();

    if (lane >= 32) return;
    const int j = lane >> 1;
    const int h = lane & 1;

    C2 st[8];
#pragma unroll
    for (int i = 0; i < 8; ++i) st[i] = C2{0.f, 0.f};
    if ((j >> 3) == h) st[j & 7].re = 1.f;

#define APPLY_PAIR(i0, i1)                                                     \
    {                                                                          \
        C2 a0 = st[i0], a1 = st[i1];                                           \
        st[i0].re = U00.re*a0.re - U00.im*a0.im + U01.re*a1.re - U01.im*a1.im; \
        st[i0].im = U00.re*a0.im + U00.im*a0.re + U01.re*a1.im + U01.im*a1.re; \
        st[i1].re = U10.re*a0.re - U10.im*a0.im + U11.re*a1.re - U11.im*a1.im; \
        st[i1].im = U10.re*a0.im + U10.im*a0.re + U11.re*a1.im + U11.im*a1.re; \
    }
#define SWAPST(a, b) { C2 t_ = st[a]; st[a] = st[b]; st[b] = t_; }

#pragma unroll
    for (int l = 0; l < NL; ++l) {
        {   // CNOT(q0 mask8, q1 mask4): if h==1, permute i <-> i^4
            C2 ns[8];
#pragma unroll
            for (int i = 0; i < 8; ++i) {
                ns[i].re = h ? st[i ^ 4].re : st[i].re;
                ns[i].im = h ? st[i ^ 4].im : st[i].im;
            }
#pragma unroll
            for (int i = 0; i < 8; ++i) st[i] = ns[i];
        }
        SWAPST(4, 6) SWAPST(5, 7)           // CNOT(q1, q2)
        SWAPST(2, 3) SWAPST(6, 7)           // CNOT(q2, q3)
#pragma unroll
        for (int i = 1; i < 8; i += 2) {    // CNOT(q3, q0)
            st[i].re = __shfl_xor(st[i].re, 1);
            st[i].im = __shfl_xor(st[i].im, 1);
        }
        {   // qubit 0 gate (cross-lane)
            const float* u = &sU[(l * NQ + 0) * 8];
            C2 U00{u[0], u[1]}, U01{u[2], u[3]}, U10{u[4], u[5]}, U11{u[6], u[7]};
            C2 Ud = h ? U11 : U00;
            C2 Uo = h ? U10 : U01;
#pragma unroll
            for (int i = 0; i < 8; ++i) {
                C2 p{__shfl_xor(st[i].re, 1), __shfl_xor(st[i].im, 1)};
                C2 a = st[i];
                st[i].re = Ud.re*a.re - Ud.im*a.im + Uo.re*p.re - Uo.im*p.im;
                st[i].im = Ud.re*a.im + Ud.im*a.re + Uo.re*p.im + Uo.im*p.re;
            }
        }
        {   // qubit 1 gate
            const float* u = &sU[(l * NQ + 1) * 8];
            C2 U00{u[0], u[1]}, U01{u[2], u[3]}, U10{u[4], u[5]}, U11{u[6], u[7]};
            APPLY_PAIR(0, 4) APPLY_PAIR(1, 5) APPLY_PAIR(2, 6) APPLY_PAIR(3, 7)
        }
        {   // qubit 2 gate
            const float* u = &sU[(l * NQ + 2) * 8];
            C2 U00{u[0], u[1]}, U01{u[2], u[3]}, U10{u[4], u[5]}, U11{u[6], u[7]};
            APPLY_PAIR(0, 2) APPLY_PAIR(1, 3) APPLY_PAIR(4, 6) APPLY_PAIR(5, 7)
        }
        {   // qubit 3 gate
            const float* u = &sU[(l * NQ + 3) * 8];
            C2 U00{u[0], u[1]}, U01{u[2], u[3]}, U10{u[4], u[5]}, U11{u[6], u[7]};
            APPLY_PAIR(0, 1) APPLY_PAIR(2, 3) APPLY_PAIR(4, 5) APPLY_PAIR(6, 7)
        }
    }

    const int p4 = __popc(j) & 3;
    const float fr = (p4 == 0) ? 1.f : (p4 == 2) ? -1.f : 0.f;
    const float fi = (p4 == 1) ? -1.f : (p4 == 3) ? 1.f : 0.f;
#pragma unroll
    for (int i = 0; i < 8; ++i) {
        const int r = h * 8 + i;
        float re = st[i].re * fr - st[i].im * fi;
        float im = st[i].re * fi + st[i].im * fr;
        V[(r * 16 + j) * 2 + 0] = re;
        V[(r * 16 + j) * 2 + 1] = im;
    }
#undef APPLY_PAIR
#undef SWAPST
}

// ---------------------------------------------------------------------------
// Main kernel: V rows are wave-uniform -> load them with s_load_dwordx16 into
// SGPRs (scalar K$, issued once per wave, zero LDS, zero bank conflicts).
// The s_waitcnt is fused into the SAME asm as the loads (SMEM completes
// out-of-order; lgkmcnt(0) only, and a separate-waitcnt asm can be bypassed
// by register-only consumers). v_fma uses the one allowed SGPR operand.
// ---------------------------------------------------------------------------
__global__ __launch_bounds__(256) void qmain_kernel(const float4* __restrict__ x,
                                                    const float* __restrict__ V,
                                                    float4* __restrict__ out) {
    const int tid = threadIdx.x;
    const int base = blockIdx.x * (256 * EPT) + tid;

    float m[EPT][16];
#pragma unroll
    for (int e = 0; e < EPT; ++e) {
        float4 xv = x[base + e * 256];
        float c0, s0, c1, s1, c2, s2, c3, s3;
        __sincosf(0.5f * xv.x, &s0, &c0);
        __sincosf(0.5f * xv.y, &s1, &c1);
        __sincosf(0.5f * xv.z, &s2, &c2);
        __sincosf(0.5f * xv.w, &s3, &c3);
        float ab[4];
        ab[0] = c0 * c1; ab[1] = c0 * s1; ab[2] = s0 * c1; ab[3] = s0 * s1;
        float abc[8];
#pragma unroll
        for (int k = 0; k < 4; ++k) { abc[2 * k] = ab[k] * c2; abc[2 * k + 1] = ab[k] * s2; }
#pragma unroll
        for (int k = 0; k < 8; ++k) { m[e][2 * k] = abc[k] * c3; m[e][2 * k + 1] = abc[k] * s3; }
    }

    float ev[EPT][4];
#pragma unroll
    for (int e = 0; e < EPT; ++e)
#pragma unroll
        for (int q = 0; q < 4; ++q) ev[e][q] = 0.f;

#pragma unroll
    for (int r = 0; r < 16; ++r) {
        const float* rowp = V + r * 32;   // 32 floats: col c -> (re,im) at 2c,2c+1
        f32x16 pa, pb;                    // cols 0..7 | cols 8..15, in SGPRs
        asm volatile("s_load_dwordx16 %0, %2, 0x0\n\t"
                     "s_load_dwordx16 %1, %2, 0x40\n\t"
                     "s_waitcnt lgkmcnt(0)"
                     : "=s"(pa), "=s"(pb)
                     : "s"(rowp));
#pragma unroll
        for (int e = 0; e < EPT; ++e) {
            float re = 0.f, im = 0.f;
#pragma unroll
            for (int c = 0; c < 8; ++c) {
                re = __builtin_fmaf(m[e][c], pa[2 * c],     re);
                im = __builtin_fmaf(m[e][c], pa[2 * c + 1], im);
            }
#pragma unroll
            for (int c = 0; c < 8; ++c) {
                re = __builtin_fmaf(m[e][8 + c], pb[2 * c],     re);
                im = __builtin_fmaf(m[e][8 + c], pb[2 * c + 1], im);
            }
            float p = __builtin_fmaf(re, re, im * im);
            if (r & 8) ev[e][0] -= p; else ev[e][0] += p;
            if (r & 4) ev[e][1] -= p; else ev[e][1] += p;
            if (r & 2) ev[e][2] -= p; else ev[e][2] += p;
            if (r & 1) ev[e][3] -= p; else ev[e][3] += p;
        }
    }

#pragma unroll
    for (int e = 0; e < EPT; ++e) {
        out[base + e * 256] = make_float4(ev[e][0], ev[e][1], ev[e][2], ev[e][3]);
    }
}

extern "C" void kernel_launch(void* const* d_in, const int* in_sizes, int n_in,
                              void* d_out, int out_size, void* d_ws, size_t ws_size,
                              hipStream_t stream) {
    const float4* x = (const float4*)d_in[0];   // [B,4] f32
    const float*  w = (const float*)d_in[1];    // [6,4,3] f32
    float* V = (float*)d_ws;                    // 16*16*2 floats = 2 KB scratch
    float4* out = (float4*)d_out;               // [B,4] f32

    prep_kernel<<<1, 64, 0, stream>>>(w, V);
    const int blocks = BATCH / (256 * EPT);     // 512
    qmain_kernel<<<blocks, 256, 0, stream>>>(x, V, out);
}

// Round 5
// 27.224 us; speedup vs baseline: 1.8202x; 1.3971x over previous
//
#include <hip/hip_runtime.h>
#include <math.h>

#define NQ 4
#define NL 6
#define BATCH 524288

struct C2 { float re, im; };

__device__ __forceinline__ C2 cmul(C2 a, C2 b) {
    return C2{ __builtin_fmaf(a.re, b.re, -a.im * b.im),
               __builtin_fmaf(a.re, b.im,  a.im * b.re) };
}

// ---------------------------------------------------------------------------
// Prep kernel (parallel, 1 block x 64 threads) — unchanged (verified R2-R4).
// Phase 1: lanes 0..23 build fused U = RZ*RY*RX gates -> LDS.
// Phase 2: lanes 0..31 (lane = 2*j + h) evolve basis column j; 8 complex
// amps in registers; cross-half ops via __shfl_xor. Folds (-i)^popcount(j)
// and stores V[r][j] interleaved (re,im) at V[(r*16+j)*2 + {0,1}].
// ---------------------------------------------------------------------------
__global__ __launch_bounds__(64) void prep_kernel(const float* __restrict__ w,
                                                  float* __restrict__ V) {
    __shared__ float sU[NL * NQ * 8];
    const int lane = threadIdx.x;

    if (lane < NL * NQ) {
        const float a = w[lane * 3 + 0];
        const float b = w[lane * 3 + 1];
        const float g = w[lane * 3 + 2];
        float ca, sa, cb, sb, cg, sg;
        sincosf(0.5f * a, &sa, &ca);
        sincosf(0.5f * b, &sb, &cb);
        sincosf(0.5f * g, &sg, &cg);
        C2 M00{cb * ca,  sb * sa};
        C2 M01{-sb * ca, -cb * sa};
        C2 M10{sb * ca,  -cb * sa};
        C2 M11{cb * ca,  -sb * sa};
        C2 em{cg, -sg}, ep{cg, sg};
        C2 U00 = cmul(em, M00), U01 = cmul(em, M01);
        C2 U10 = cmul(ep, M10), U11 = cmul(ep, M11);
        float* o = &sU[lane * 8];
        o[0] = U00.re; o[1] = U00.im; o[2] = U01.re; o[3] = U01.im;
        o[4] = U10.re; o[5] = U10.im; o[6] = U11.re; o[7] = U11.im;
    }
    __syncthreads();

    if (lane >= 32) return;
    const int j = lane >> 1;
    const int h = lane & 1;

    C2 st[8];
#pragma unroll
    for (int i = 0; i < 8; ++i) st[i] = C2{0.f, 0.f};
    if ((j >> 3) == h) st[j & 7].re = 1.f;

#define APPLY_PAIR(i0, i1)                                                     \
    {                                                                          \
        C2 a0 = st[i0], a1 = st[i1];                                           \
        st[i0].re = U00.re*a0.re - U00.im*a0.im + U01.re*a1.re - U01.im*a1.im; \
        st[i0].im = U00.re*a0.im + U00.im*a0.re + U01.re*a1.im + U01.im*a1.re; \
        st[i1].re = U10.re*a0.re - U10.im*a0.im + U11.re*a1.re - U11.im*a1.im; \
        st[i1].im = U10.re*a0.im + U10.im*a0.re + U11.re*a1.im + U11.im*a1.re; \
    }
#define SWAPST(a, b) { C2 t_ = st[a]; st[a] = st[b]; st[b] = t_; }

#pragma unroll
    for (int l = 0; l < NL; ++l) {
        {   // CNOT(q0 mask8, q1 mask4): if h==1, permute i <-> i^4
            C2 ns[8];
#pragma unroll
            for (int i = 0; i < 8; ++i) {
                ns[i].re = h ? st[i ^ 4].re : st[i].re;
                ns[i].im = h ? st[i ^ 4].im : st[i].im;
            }
#pragma unroll
            for (int i = 0; i < 8; ++i) st[i] = ns[i];
        }
        SWAPST(4, 6) SWAPST(5, 7)           // CNOT(q1, q2)
        SWAPST(2, 3) SWAPST(6, 7)           // CNOT(q2, q3)
#pragma unroll
        for (int i = 1; i < 8; i += 2) {    // CNOT(q3, q0)
            st[i].re = __shfl_xor(st[i].re, 1);
            st[i].im = __shfl_xor(st[i].im, 1);
        }
        {   // qubit 0 gate (cross-lane)
            const float* u = &sU[(l * NQ + 0) * 8];
            C2 U00{u[0], u[1]}, U01{u[2], u[3]}, U10{u[4], u[5]}, U11{u[6], u[7]};
            C2 Ud = h ? U11 : U00;
            C2 Uo = h ? U10 : U01;
#pragma unroll
            for (int i = 0; i < 8; ++i) {
                C2 p{__shfl_xor(st[i].re, 1), __shfl_xor(st[i].im, 1)};
                C2 a = st[i];
                st[i].re = Ud.re*a.re - Ud.im*a.im + Uo.re*p.re - Uo.im*p.im;
                st[i].im = Ud.re*a.im + Ud.im*a.re + Uo.re*p.im + Uo.im*p.re;
            }
        }
        {   // qubit 1 gate
            const float* u = &sU[(l * NQ + 1) * 8];
            C2 U00{u[0], u[1]}, U01{u[2], u[3]}, U10{u[4], u[5]}, U11{u[6], u[7]};
            APPLY_PAIR(0, 4) APPLY_PAIR(1, 5) APPLY_PAIR(2, 6) APPLY_PAIR(3, 7)
        }
        {   // qubit 2 gate
            const float* u = &sU[(l * NQ + 2) * 8];
            C2 U00{u[0], u[1]}, U01{u[2], u[3]}, U10{u[4], u[5]}, U11{u[6], u[7]};
            APPLY_PAIR(0, 2) APPLY_PAIR(1, 3) APPLY_PAIR(4, 6) APPLY_PAIR(5, 7)
        }
        {   // qubit 3 gate
            const float* u = &sU[(l * NQ + 3) * 8];
            C2 U00{u[0], u[1]}, U01{u[2], u[3]}, U10{u[4], u[5]}, U11{u[6], u[7]};
            APPLY_PAIR(0, 1) APPLY_PAIR(2, 3) APPLY_PAIR(4, 5) APPLY_PAIR(6, 7)
        }
    }

    const int p4 = __popc(j) & 3;
    const float fr = (p4 == 0) ? 1.f : (p4 == 2) ? -1.f : 0.f;
    const float fi = (p4 == 1) ? -1.f : (p4 == 3) ? 1.f : 0.f;
#pragma unroll
    for (int i = 0; i < 8; ++i) {
        const int r = h * 8 + i;
        float re = st[i].re * fr - st[i].im * fi;
        float im = st[i].re * fi + st[i].im * fr;
        V[(r * 16 + j) * 2 + 0] = re;
        V[(r * 16 + j) * 2 + 1] = im;
    }
#undef APPLY_PAIR
#undef SWAPST
}

// ---------------------------------------------------------------------------
// Main kernel: EPT=1, 2048 blocks x 256 threads (8192 waves -> high
// occupancy for latency hiding). No LDS, no inline asm: V is read with
// plain wave-uniform loads from global (2 KB, L1/K$-resident after first
// touch); the compiler schedules the scalar/vector loads and waits across
// row iterations. Each fma uses at most one uniform (SGPR) operand - legal.
// ---------------------------------------------------------------------------
__global__ __launch_bounds__(256, 4) void qmain_kernel(const float4* __restrict__ x,
                                                       const float* __restrict__ V,
                                                       float4* __restrict__ out) {
    const int gid = blockIdx.x * 256 + threadIdx.x;

    const float4 xv = x[gid];
    float c0, s0, c1, s1, c2, s2, c3, s3;
    __sincosf(0.5f * xv.x, &s0, &c0);
    __sincosf(0.5f * xv.y, &s1, &c1);
    __sincosf(0.5f * xv.z, &s2, &c2);
    __sincosf(0.5f * xv.w, &s3, &c3);

    float m[16];
    {
        float ab[4];
        ab[0] = c0 * c1; ab[1] = c0 * s1; ab[2] = s0 * c1; ab[3] = s0 * s1;
        float abc[8];
#pragma unroll
        for (int k = 0; k < 4; ++k) { abc[2 * k] = ab[k] * c2; abc[2 * k + 1] = ab[k] * s2; }
#pragma unroll
        for (int k = 0; k < 8; ++k) { m[2 * k] = abc[k] * c3; m[2 * k + 1] = abc[k] * s3; }
    }

    float ev0 = 0.f, ev1 = 0.f, ev2 = 0.f, ev3 = 0.f;

#pragma unroll
    for (int r = 0; r < 16; ++r) {
        const float4* row = reinterpret_cast<const float4*>(V + r * 32);
        float re = 0.f, im = 0.f;
#pragma unroll
        for (int k = 0; k < 8; ++k) {
            const float4 v4 = row[k];   // wave-uniform: (re,im) of cols 2k, 2k+1
            re = __builtin_fmaf(m[2 * k],     v4.x, re);
            im = __builtin_fmaf(m[2 * k],     v4.y, im);
            re = __builtin_fmaf(m[2 * k + 1], v4.z, re);
            im = __builtin_fmaf(m[2 * k + 1], v4.w, im);
        }
        const float p = __builtin_fmaf(re, re, im * im);
        ev0 += (r & 8) ? -p : p;
        ev1 += (r & 4) ? -p : p;
        ev2 += (r & 2) ? -p : p;
        ev3 += (r & 1) ? -p : p;
    }

    out[gid] = make_float4(ev0, ev1, ev2, ev3);
}

extern "C" void kernel_launch(void* const* d_in, const int* in_sizes, int n_in,
                              void* d_out, int out_size, void* d_ws, size_t ws_size,
                              hipStream_t stream) {
    const float4* x = (const float4*)d_in[0];   // [B,4] f32
    const float*  w = (const float*)d_in[1];    // [6,4,3] f32
    float* V = (float*)d_ws;                    // 16*16*2 floats = 2 KB scratch
    float4* out = (float4*)d_out;               // [B,4] f32

    prep_kernel<<<1, 64, 0, stream>>>(w, V);
    qmain_kernel<<<BATCH / 256, 256, 0, stream>>>(x, V, out);
}